// Round 3
// baseline (1827.460 us; speedup 1.0000x reference)
//
#include <hip/hip_runtime.h>

#define BB 128
#define TT 2048
#define HH 64

__device__ __forceinline__ float sigm(float v) {
    return __builtin_amdgcn_rcpf(1.0f + __expf(-v));
}
__device__ __forceinline__ float ftanh(float v) {
    float e = __expf(-2.0f * fabsf(v));
    float r = (1.0f - e) * __builtin_amdgcn_rcpf(1.0f + e);
    return copysignf(r, v);
}

// Keep a float4 alive in VGPRs: opaque asm redefinition blocks the register
// allocator's "rematerialize by re-loading from global" heuristic, which in
// R1/R2 caused every wave to re-fetch its 48KB weight panel from L2 each
// timestep (VGPR_Count 120 < the 192 required).
#define PIN4(v) asm volatile("" : "+v"((v).x), "+v"((v).y), "+v"((v).z), "+v"((v).w))

// One block per batch. 3 waves:
//   wave0: h1(i)   = GRU1(h1(i-1), x(i))        [hg1 in registers]
//   wave1: xg(i-1) = Wih1*h1(i-1)+bih1          [from LDS h1, parity buffer]
//   wave2: h2(i-2) = GRU2(h2(i-3), xg(i-2))     [hg2 in registers]
// Single barrier per iteration: every wave reads only LDS data written in
// PREVIOUS iterations (parity double-buffers for h1/xg; h2b is wave2-private).
// fc head: wave2 drops h2 rows into a 128-slot ring; wave1 flushes 64
// outputs every 64 iters (ring distance 128 >> 64 => no overlap race).
__global__ __launch_bounds__(192, 1)
void gru_fused(const float* __restrict__ x,
               const float* __restrict__ Wih0, const float* __restrict__ Whh0,
               const float* __restrict__ bih0, const float* __restrict__ bhh0,
               const float* __restrict__ Wih1, const float* __restrict__ Whh1,
               const float* __restrict__ bih1, const float* __restrict__ bhh1,
               const float* __restrict__ fcw, const float* __restrict__ fcb,
               float* __restrict__ out)
{
    const int t  = threadIdx.x;
    const int wv = t >> 6;          // wave id 0..2
    const int j  = t & 63;          // lane
    const int b  = blockIdx.x;

    __shared__ __align__(16) float xs[TT * 2];        // 16 KB input
    __shared__ __align__(16) float h1b[2][HH];        // parity buffers
    __shared__ __align__(16) float h2b[HH];           // wave2-private
    __shared__ __align__(16) float xgb[2][3 * HH];    // parity buffers
    __shared__ __align__(16) float fwS[HH];
    __shared__ float ring[128][65];                   // h2 history, stride 65

    // ---- this wave's 3 rows of its recurrent matrix -> 48 float4 regs ----
    const float* Wm = (wv == 0) ? Whh0 : (wv == 1) ? Wih1 : Whh1;
    float4 w[48];
    #pragma unroll
    for (int r = 0; r < 3; ++r) {
        const float4* p = (const float4*)(Wm + (r * HH + j) * HH);
        #pragma unroll
        for (int k = 0; k < 16; ++k) w[r * 16 + k] = p[k];
    }
    #pragma unroll
    for (int k = 0; k < 48; ++k) PIN4(w[k]);   // force true register residency

    // dot-phase biases (bhh0 / bih1 / bhh1 rows j, 64+j, 128+j)
    float ba, bbv, bc;
    if (wv == 0)      { ba = bhh0[j]; bbv = bhh0[HH + j]; bc = bhh0[2*HH + j]; }
    else if (wv == 1) { ba = bih1[j]; bbv = bih1[HH + j]; bc = bih1[2*HH + j]; }
    else              { ba = bhh1[j]; bbv = bhh1[HH + j]; bc = bhh1[2*HH + j]; }
    // wave0 input-side constants
    float wi0=0, wi1=0, wi2=0, wi3=0, wi4=0, wi5=0, bi0=0, bi1=0, bi2=0;
    if (wv == 0) {
        wi0 = Wih0[j*2];          wi1 = Wih0[j*2 + 1];
        wi2 = Wih0[(HH+j)*2];     wi3 = Wih0[(HH+j)*2 + 1];
        wi4 = Wih0[(2*HH+j)*2];   wi5 = Wih0[(2*HH+j)*2 + 1];
        bi0 = bih0[j]; bi1 = bih0[HH + j]; bi2 = bih0[2*HH + j];
    }
    const float fcbv = fcb[0];

    // ---- preload x, zero state ----
    {
        const float4* xp  = (const float4*)(x + (size_t)b * TT * 2);
        float4*       xsp = (float4*)xs;
        for (int i = t; i < TT * 2 / 4; i += 192) xsp[i] = xp[i];
    }
    if (t < HH) { h1b[0][t] = 0.f; h1b[1][t] = 0.f; h2b[t] = 0.f; fwS[t] = fcw[t]; }
    xgb[0][t] = 0.f; xgb[1][t] = 0.f;

    float hown = 0.f;   // wave0: h1[j];  wave2: h2[j]  (register-resident)

    for (int i = 0; i < TT + 2; ++i) {
        __syncthreads();
        const bool act = (wv == 0) ? (i < TT)
                       : (wv == 1) ? (i >= 1 && i < TT + 1)
                                   : (i >= 2);
        if (act) {
            // early reads (stable data from previous iterations)
            float x0 = 0.f, x1 = 0.f, g0 = 0.f, g1 = 0.f, g2 = 0.f;
            if (wv == 0) { x0 = xs[2*i]; x1 = xs[2*i + 1]; }
            if (wv == 2) {
                const float* xg = xgb[(i - 2) & 1];
                g0 = xg[j]; g1 = xg[HH + j]; g2 = xg[2*HH + j];
            }
            const float4* hb = (wv == 2) ? (const float4*)h2b
                                         : (const float4*)h1b[(i - 1) & 1];
            float a0 = ba, a1 = 0.f, b0 = bbv, b1 = 0.f, c0 = bc, c1 = 0.f;
            #pragma unroll
            for (int k = 0; k < 16; k += 2) {
                float4 hA = hb[k], hB = hb[k + 1];
                a0 += w[k   ].x*hA.x + w[k   ].y*hA.y + w[k   ].z*hA.z + w[k   ].w*hA.w;
                a1 += w[k+1 ].x*hB.x + w[k+1 ].y*hB.y + w[k+1 ].z*hB.z + w[k+1 ].w*hB.w;
                b0 += w[16+k].x*hA.x + w[16+k].y*hA.y + w[16+k].z*hA.z + w[16+k].w*hA.w;
                b1 += w[17+k].x*hB.x + w[17+k].y*hB.y + w[17+k].z*hB.z + w[17+k].w*hB.w;
                c0 += w[32+k].x*hA.x + w[32+k].y*hA.y + w[32+k].z*hA.z + w[32+k].w*hA.w;
                c1 += w[33+k].x*hB.x + w[33+k].y*hB.y + w[33+k].z*hB.z + w[33+k].w*hB.w;
            }
            const float A = a0 + a1, Bv = b0 + b1, C = c0 + c1;

            if (wv == 0) {                       // layer-1 gates, step i
                float r = sigm (wi0*x0 + wi1*x1 + bi0 + A);
                float z = sigm (wi2*x0 + wi3*x1 + bi1 + Bv);
                float n = ftanh(wi4*x0 + wi5*x1 + bi2 + r * C);
                hown = (1.f - z) * n + z * hown;
                h1b[i & 1][j] = hown;
            } else if (wv == 1) {                // xg for step i-1
                float* xg = xgb[(i - 1) & 1];
                xg[j] = A; xg[HH + j] = Bv; xg[2*HH + j] = C;
            } else {                             // layer-2 gates, step i-2
                float r = sigm (g0 + A);
                float z = sigm (g1 + Bv);
                float n = ftanh(g2 + r * C);
                hown = (1.f - z) * n + z * hown;
                h2b[j] = hown;
                ring[(i - 2) & 127][j] = hown;
            }
        }
        // fc-head flush: wave1, every 64 iters, 64 finished timesteps
        if (wv == 1 && i >= 66 && ((i - 66) & 63) == 0) {
            const int tt = ((i - 66) >> 6) * 64 + j;     // chunk c, lane j
            const float* rr = ring[tt & 127];
            float acc0 = 0.f, acc1 = 0.f;
            #pragma unroll
            for (int k = 0; k < 64; k += 2) {
                acc0 += rr[k]     * fwS[k];
                acc1 += rr[k + 1] * fwS[k + 1];
            }
            out[(size_t)b * TT + tt] = acc0 + acc1 + fcbv;
        }
    }
    __syncthreads();
    if (wv == 1) {                                // final chunk: t = 1984..2047
        const int tt = 31 * 64 + j;
        const float* rr = ring[tt & 127];
        float acc0 = 0.f, acc1 = 0.f;
        #pragma unroll
        for (int k = 0; k < 64; k += 2) {
            acc0 += rr[k]     * fwS[k];
            acc1 += rr[k + 1] * fwS[k + 1];
        }
        out[(size_t)b * TT + tt] = acc0 + acc1 + fcbv;
    }
}

extern "C" void kernel_launch(void* const* d_in, const int* in_sizes, int n_in,
                              void* d_out, int out_size, void* d_ws, size_t ws_size,
                              hipStream_t stream) {
    const float* x    = (const float*)d_in[0];
    const float* Wih0 = (const float*)d_in[1];
    const float* Whh0 = (const float*)d_in[2];
    const float* bih0 = (const float*)d_in[3];
    const float* bhh0 = (const float*)d_in[4];
    const float* Wih1 = (const float*)d_in[5];
    const float* Whh1 = (const float*)d_in[6];
    const float* bih1 = (const float*)d_in[7];
    const float* bhh1 = (const float*)d_in[8];
    const float* fcw  = (const float*)d_in[9];
    const float* fcb  = (const float*)d_in[10];
    float* out = (float*)d_out;

    gru_fused<<<BB, 192, 0, stream>>>(x, Wih0, Whh0, bih0, bhh0,
                                      Wih1, Whh1, bih1, bhh1, fcw, fcb, out);
}

// Round 4
// 1824.868 us; speedup vs baseline: 1.0014x; 1.0014x over previous
//
#include <hip/hip_runtime.h>

#define BB 128
#define TT 2048
#define HH 64

__device__ __forceinline__ float sigm(float v) {
    return __builtin_amdgcn_rcpf(1.0f + __expf(-v));
}
__device__ __forceinline__ float ftanh(float v) {
    float e = __expf(-2.0f * fabsf(v));
    float r = (1.0f - e) * __builtin_amdgcn_rcpf(1.0f + e);
    return copysignf(r, v);
}

// Keep a float4 alive in VGPRs: opaque asm redefinition blocks the register
// allocator's "rematerialize by re-loading" heuristic.
#define PIN4(v) asm volatile("" : "+v"((v).x), "+v"((v).y), "+v"((v).z), "+v"((v).w))

// One block per batch. 3 waves:
//   wave0: h1(i)   = GRU1(h1(i-1), x(i))        [hg1 in registers]
//   wave1: xg(i-1) = Wih1*h1(i-1)+bih1          [from LDS h1, parity buffer]
//   wave2: h2(i-2) = GRU2(h2(i-3), xg(i-2))     [hg2 in registers]
// Single barrier per iteration: every wave reads only LDS data written in
// PREVIOUS iterations (parity double-buffers for h1/xg; h2b is wave2-private).
// fc head: wave2 drops h2 rows into a 128-slot ring; wave1 flushes 64
// outputs every 64 iters.
//
// amdgpu_waves_per_eu(1,1): grid=128 blocks on 256 CUs -> 1 wave/SIMD is the
// real occupancy. Pinning MAX waves/EU to 1 gives the register allocator the
// full 512-VGPR budget; without it the backend's occupancy heuristic capped
// allocation at ~120 VGPRs and spilled the 192 pinned weight values to
// scratch (R2/R3: L2-bound at ~147KB/block/iter, 1.8ms).
__global__ __launch_bounds__(192)
__attribute__((amdgpu_waves_per_eu(1, 1)))
void gru_fused(const float* __restrict__ x,
               const float* __restrict__ Wih0, const float* __restrict__ Whh0,
               const float* __restrict__ bih0, const float* __restrict__ bhh0,
               const float* __restrict__ Wih1, const float* __restrict__ Whh1,
               const float* __restrict__ bih1, const float* __restrict__ bhh1,
               const float* __restrict__ fcw, const float* __restrict__ fcb,
               float* __restrict__ out)
{
    const int t  = threadIdx.x;
    const int wv = t >> 6;          // wave id 0..2
    const int j  = t & 63;          // lane
    const int b  = blockIdx.x;

    __shared__ __align__(16) float xs[TT * 2];        // 16 KB input
    __shared__ __align__(16) float h1b[2][HH];        // parity buffers
    __shared__ __align__(16) float h2b[HH];           // wave2-private
    __shared__ __align__(16) float xgb[2][3 * HH];    // parity buffers
    __shared__ __align__(16) float fwS[HH];
    __shared__ float ring[128][65];                   // h2 history, stride 65

    // ---- this wave's 3 rows of its recurrent matrix -> 48 float4 regs ----
    const float* Wm = (wv == 0) ? Whh0 : (wv == 1) ? Wih1 : Whh1;
    float4 w[48];
    #pragma unroll
    for (int r = 0; r < 3; ++r) {
        const float4* p = (const float4*)(Wm + (r * HH + j) * HH);
        #pragma unroll
        for (int k = 0; k < 16; ++k) w[r * 16 + k] = p[k];
    }
    #pragma unroll
    for (int k = 0; k < 48; ++k) PIN4(w[k]);   // force true register residency

    // dot-phase biases (bhh0 / bih1 / bhh1 rows j, 64+j, 128+j)
    float ba, bbv, bc;
    if (wv == 0)      { ba = bhh0[j]; bbv = bhh0[HH + j]; bc = bhh0[2*HH + j]; }
    else if (wv == 1) { ba = bih1[j]; bbv = bih1[HH + j]; bc = bih1[2*HH + j]; }
    else              { ba = bhh1[j]; bbv = bhh1[HH + j]; bc = bhh1[2*HH + j]; }
    // wave0 input-side constants
    float wi0=0, wi1=0, wi2=0, wi3=0, wi4=0, wi5=0, bi0=0, bi1=0, bi2=0;
    if (wv == 0) {
        wi0 = Wih0[j*2];          wi1 = Wih0[j*2 + 1];
        wi2 = Wih0[(HH+j)*2];     wi3 = Wih0[(HH+j)*2 + 1];
        wi4 = Wih0[(2*HH+j)*2];   wi5 = Wih0[(2*HH+j)*2 + 1];
        bi0 = bih0[j]; bi1 = bih0[HH + j]; bi2 = bih0[2*HH + j];
    }
    const float fcbv = fcb[0];

    // ---- preload x, zero state ----
    {
        const float4* xp  = (const float4*)(x + (size_t)b * TT * 2);
        float4*       xsp = (float4*)xs;
        for (int i = t; i < TT * 2 / 4; i += 192) xsp[i] = xp[i];
    }
    if (t < HH) { h1b[0][t] = 0.f; h1b[1][t] = 0.f; h2b[t] = 0.f; fwS[t] = fcw[t]; }
    xgb[0][t] = 0.f; xgb[1][t] = 0.f;

    float hown = 0.f;   // wave0: h1[j];  wave2: h2[j]  (register-resident)

    for (int i = 0; i < TT + 2; ++i) {
        __syncthreads();
        const bool act = (wv == 0) ? (i < TT)
                       : (wv == 1) ? (i >= 1 && i < TT + 1)
                                   : (i >= 2);
        if (act) {
            // early reads (stable data from previous iterations)
            float x0 = 0.f, x1 = 0.f, g0 = 0.f, g1 = 0.f, g2 = 0.f;
            if (wv == 0) { x0 = xs[2*i]; x1 = xs[2*i + 1]; }
            if (wv == 2) {
                const float* xg = xgb[(i - 2) & 1];
                g0 = xg[j]; g1 = xg[HH + j]; g2 = xg[2*HH + j];
            }
            const float4* hb = (wv == 2) ? (const float4*)h2b
                                         : (const float4*)h1b[(i - 1) & 1];
            float a0 = ba, a1 = 0.f, b0 = bbv, b1 = 0.f, c0 = bc, c1 = 0.f;
            #pragma unroll
            for (int k = 0; k < 16; k += 2) {
                float4 hA = hb[k], hB = hb[k + 1];
                a0 += w[k   ].x*hA.x + w[k   ].y*hA.y + w[k   ].z*hA.z + w[k   ].w*hA.w;
                a1 += w[k+1 ].x*hB.x + w[k+1 ].y*hB.y + w[k+1 ].z*hB.z + w[k+1 ].w*hB.w;
                b0 += w[16+k].x*hA.x + w[16+k].y*hA.y + w[16+k].z*hA.z + w[16+k].w*hA.w;
                b1 += w[17+k].x*hB.x + w[17+k].y*hB.y + w[17+k].z*hB.z + w[17+k].w*hB.w;
                c0 += w[32+k].x*hA.x + w[32+k].y*hA.y + w[32+k].z*hA.z + w[32+k].w*hA.w;
                c1 += w[33+k].x*hB.x + w[33+k].y*hB.y + w[33+k].z*hB.z + w[33+k].w*hB.w;
            }
            const float A = a0 + a1, Bv = b0 + b1, C = c0 + c1;

            if (wv == 0) {                       // layer-1 gates, step i
                float r = sigm (wi0*x0 + wi1*x1 + bi0 + A);
                float z = sigm (wi2*x0 + wi3*x1 + bi1 + Bv);
                float n = ftanh(wi4*x0 + wi5*x1 + bi2 + r * C);
                hown = (1.f - z) * n + z * hown;
                h1b[i & 1][j] = hown;
            } else if (wv == 1) {                // xg for step i-1
                float* xg = xgb[(i - 1) & 1];
                xg[j] = A; xg[HH + j] = Bv; xg[2*HH + j] = C;
            } else {                             // layer-2 gates, step i-2
                float r = sigm (g0 + A);
                float z = sigm (g1 + Bv);
                float n = ftanh(g2 + r * C);
                hown = (1.f - z) * n + z * hown;
                h2b[j] = hown;
                ring[(i - 2) & 127][j] = hown;
            }
        }
        // fc-head flush: wave1, every 64 iters, 64 finished timesteps
        if (wv == 1 && i >= 66 && ((i - 66) & 63) == 0) {
            const int tt = ((i - 66) >> 6) * 64 + j;     // chunk c, lane j
            const float* rr = ring[tt & 127];
            float acc0 = 0.f, acc1 = 0.f;
            #pragma unroll
            for (int k = 0; k < 64; k += 2) {
                acc0 += rr[k]     * fwS[k];
                acc1 += rr[k + 1] * fwS[k + 1];
            }
            out[(size_t)b * TT + tt] = acc0 + acc1 + fcbv;
        }
    }
    __syncthreads();
    if (wv == 1) {                                // final chunk: t = 1984..2047
        const int tt = 31 * 64 + j;
        const float* rr = ring[tt & 127];
        float acc0 = 0.f, acc1 = 0.f;
        #pragma unroll
        for (int k = 0; k < 64; k += 2) {
            acc0 += rr[k]     * fwS[k];
            acc1 += rr[k + 1] * fwS[k + 1];
        }
        out[(size_t)b * TT + tt] = acc0 + acc1 + fcbv;
    }
}

extern "C" void kernel_launch(void* const* d_in, const int* in_sizes, int n_in,
                              void* d_out, int out_size, void* d_ws, size_t ws_size,
                              hipStream_t stream) {
    const float* x    = (const float*)d_in[0];
    const float* Wih0 = (const float*)d_in[1];
    const float* Whh0 = (const float*)d_in[2];
    const float* bih0 = (const float*)d_in[3];
    const float* bhh0 = (const float*)d_in[4];
    const float* Wih1 = (const float*)d_in[5];
    const float* Whh1 = (const float*)d_in[6];
    const float* bih1 = (const float*)d_in[7];
    const float* bhh1 = (const float*)d_in[8];
    const float* fcw  = (const float*)d_in[9];
    const float* fcb  = (const float*)d_in[10];
    float* out = (float*)d_out;

    gru_fused<<<BB, 192, 0, stream>>>(x, Wih0, Whh0, bih0, bhh0,
                                      Wih1, Whh1, bih1, bhh1, fcw, fcb, out);
}